// Round 5
// baseline (1370.525 us; speedup 1.0000x reference)
//
#include <hip/hip_runtime.h>
#include <math.h>

#define NT 256
typedef _Float16 f16;
typedef _Float16 half8 __attribute__((ext_vector_type(8)));
typedef float floatx4 __attribute__((ext_vector_type(4)));

// ---------------- workspace layout (bytes) ----------------
#define WCAP_LO_OFF 200704            // Wcap_hi: 448*224*2 @ 0
#define BCAP_OFF    401408            // bcap: 448*4
#define WD1_OFF     403200            // Wd1p: 896*800*2 = 1433600
#define WD2_OFF     1836800           // Wd2p: 1433600
#define WOT_OFF     3270400           // WoT: 784*16*4 = 50176
#define HBUF_OFF    3321856           // h:  32768*800*2 = 52428800
#define D1_OFF      55750656          // d1: 32768*800*2 ; total ~108.2 MB

__device__ inline void glds16(const void* g, void* l) {
  __builtin_amdgcn_global_load_lds((const __attribute__((address_space(1))) void*)g,
                                   (__attribute__((address_space(3))) void*)l, 16, 0, 0);
}

// ---------------- prep kernels ----------------
__global__ void k_prep_wcap(const float* __restrict__ W1, const float* __restrict__ b1,
                            const float* __restrict__ W2,
                            const float* __restrict__ W3, const float* __restrict__ b3,
                            f16* __restrict__ Wch, f16* __restrict__ Wcl,
                            float* __restrict__ bcap) {
  int idx = blockIdx.x * NT + threadIdx.x;
  if (idx >= 448 * 224) return;
  int n = idx / 224, k = idx - n * 224;
  float v = 0.f;
  if (k < 196) {
    if (n < 196) {
      float s = 0.f;
      for (int f = 0; f < 196; ++f) s += W1[f * 196 + k] * W2[f * 196 + n];
      v = s;
    } else if (n == 196) {
      float s = 0.f;
      for (int f = 0; f < 196; ++f) s += b1[f] * W2[f * 196 + k];
      v = s;
    } else if (n >= 224 && n < 420) {
      v = W3[(n - 224) * 196 + k];
    }
  }
  f16 hi = (f16)v;
  Wch[idx] = hi;
  Wcl[idx] = (f16)(v - (float)hi);
  if (k == 0) bcap[n] = (n >= 224 && n < 420) ? b3[n - 224] : 0.f;
}

__global__ void k_prep_wd(const float* __restrict__ Wd, f16* __restrict__ W16) {
  int idx = blockIdx.x * NT + threadIdx.x;
  if (idx >= 896 * 800) return;
  int n = idx / 800, k = idx - n * 800;
  W16[idx] = (f16)((n < 784 && k < 784) ? Wd[n * 784 + k] : 0.f);
}

__global__ void k_prep_wo(const float* __restrict__ Wo, float* __restrict__ WoT) {
  int idx = blockIdx.x * NT + threadIdx.x;
  if (idx >= 784 * 16) return;
  int f = idx >> 4, n = idx & 15;
  WoT[idx] = (n < 10) ? Wo[n * 784 + f] : 0.f;
}

// ---------------- capsule recurrence: 8 elems/wg (M=32), 4 wg/CU ----------------
// Phase A: Y = v*G (+Z col), acc[2][4]; score reduce; softmax; Phase D: u = v*W3^T; PV.
__global__ __launch_bounds__(NT, 4)
void k_caps(const float* __restrict__ x,
            const f16* __restrict__ Wch, const f16* __restrict__ Wcl,
            const float* __restrict__ bcap,
            f16* __restrict__ hbuf) {
  __shared__ __align__(16) char smem[32384];
  f16*   vAhi  = (f16*)smem;                 // [32][232]  (14848 B)
  f16*   vAlo  = (f16*)(smem + 14848);       // [32][232]
  float* Spart = (float*)(smem + 29696);     // [4][32][4] (2048 B)
  float* Sful  = (float*)(smem + 31744);     // [32][4]    (512 B)
  float* Zl    = (float*)(smem + 32256);     // [32]       (128 B)

  const int tid  = threadIdx.x;
  const int w    = tid >> 6;
  const int lane = tid & 63;
  const int l15  = lane & 15;
  const int quad = lane >> 4;
  const int e0   = blockIdx.x * 8;

  for (int idx = tid; idx < 8 * 784; idx += NT) {
    int elem = idx / 784, r = idx - elem * 784;
    int t = r / 196, f = r - t * 196;
    float val = x[(size_t)(e0 + elem) * 784 + r];
    f16 hi = (f16)val;
    int vo = (elem * 4 + t) * 232 + f;
    vAhi[vo] = hi;
    vAlo[vo] = (f16)(val - (float)hi);
  }
  for (int p = tid; p < 32 * 36; p += NT) {
    int row = p / 36, c = 196 + (p - (p / 36) * 36);
    vAhi[row * 232 + c] = (f16)0;
    vAlo[row * 232 + c] = (f16)0;
  }
  __syncthreads();

  // u bias (constant across iterations): ntile 14+w+4j
  float ubias[4];
  #pragma unroll
  for (int j = 0; j < 4; ++j) {
    int nt = 14 + w + 4 * j;
    ubias[j] = (nt < 27) ? bcap[nt * 16 + l15] : 0.f;
  }

  #pragma unroll 1
  for (int it = 0; it < 8; ++it) {
    // ---------- Phase A: Y GEMM [32 x 208] (ntiles 0..12; Y bias == 0) ----------
    {
      floatx4 acc[2][4];
      #pragma unroll
      for (int mt = 0; mt < 2; ++mt)
        #pragma unroll
        for (int j = 0; j < 4; ++j) acc[mt][j] = (floatx4){0.f, 0.f, 0.f, 0.f};
      #pragma unroll
      for (int ks = 0; ks < 7; ++ks) {
        half8 ah[2], al[2];
        #pragma unroll
        for (int mt = 0; mt < 2; ++mt) {
          int ao = (mt * 16 + l15) * 232 + ks * 32 + quad * 8;
          ah[mt] = *(const half8*)&vAhi[ao];
          al[mt] = *(const half8*)&vAlo[ao];
        }
        #pragma unroll
        for (int j = 0; j < 4; ++j) {
          int nt = w + 4 * j;
          if (nt < 13) {                       // wave-uniform branch
            int bo_ = (nt * 16 + l15) * 224 + ks * 32 + quad * 8;
            half8 bh = *(const half8*)&Wch[bo_];
            half8 bl = *(const half8*)&Wcl[bo_];
            #pragma unroll
            for (int mt = 0; mt < 2; ++mt) {
              acc[mt][j] = __builtin_amdgcn_mfma_f32_16x16x32_f16(ah[mt], bh, acc[mt][j], 0, 0, 0);
              acc[mt][j] = __builtin_amdgcn_mfma_f32_16x16x32_f16(ah[mt], bl, acc[mt][j], 0, 0, 0);
              acc[mt][j] = __builtin_amdgcn_mfma_f32_16x16x32_f16(al[mt], bh, acc[mt][j], 0, 0, 0);
            }
          }
        }
      }
      // Z col 196 = ntile 12 (w==0, j==3), l15==4
      if (w == 0 && l15 == 4) {
        #pragma unroll
        for (int mt = 0; mt < 2; ++mt) {
          int elem = mt * 4 + quad;
          #pragma unroll
          for (int t = 0; t < 4; ++t) Zl[elem * 4 + t] = acc[mt][3][t];
        }
      }
      // score partials: S[t][s] += Y_t[col] * v_s[col]
      #pragma unroll
      for (int mt = 0; mt < 2; ++mt) {
        int elem = mt * 4 + quad;
        float part[16];
        #pragma unroll
        for (int i = 0; i < 16; ++i) part[i] = 0.f;
        #pragma unroll
        for (int j = 0; j < 4; ++j) {
          int nt = w + 4 * j;
          if (nt < 13) {
            int col = nt * 16 + l15;
            floatx4 c = acc[mt][j];
            #pragma unroll
            for (int s = 0; s < 4; ++s) {
              int vo = (elem * 4 + s) * 232 + col;
              float vv = (float)vAhi[vo] + (float)vAlo[vo];
              #pragma unroll
              for (int t = 0; t < 4; ++t) part[t * 4 + s] += c[t] * vv;
            }
          }
        }
        #pragma unroll
        for (int m = 1; m < 16; m <<= 1) {
          #pragma unroll
          for (int i = 0; i < 16; ++i) part[i] += __shfl_xor(part[i], m, 64);
        }
        if (l15 == 0) {
          #pragma unroll
          for (int i = 0; i < 16; ++i)
            Spart[(w * 32 + elem * 4 + (i >> 2)) * 4 + (i & 3)] = part[i];
        }
      }
    }
    __syncthreads();
    // ---------- softmax ----------
    if (tid < 32) {
      int row = tid, elem = row >> 2;
      float sv[4];
      #pragma unroll
      for (int s = 0; s < 4; ++s)
        sv[s] = Spart[(0 * 32 + row) * 4 + s] + Spart[(1 * 32 + row) * 4 + s] +
                Spart[(2 * 32 + row) * 4 + s] + Spart[(3 * 32 + row) * 4 + s] +
                Zl[elem * 4 + s];
      float m = fmaxf(fmaxf(sv[0], sv[1]), fmaxf(sv[2], sv[3]));
      float ex0 = __expf(sv[0] - m), ex1 = __expf(sv[1] - m);
      float ex2 = __expf(sv[2] - m), ex3 = __expf(sv[3] - m);
      float inv = 1.f / (ex0 + ex1 + ex2 + ex3);
      Sful[row * 4 + 0] = ex0 * inv;
      Sful[row * 4 + 1] = ex1 * inv;
      Sful[row * 4 + 2] = ex2 * inv;
      Sful[row * 4 + 3] = ex3 * inv;
    }
    __syncthreads();
    // ---------- Phase D: u GEMM [32 x 208] (ntiles 14..26) ----------
    floatx4 acu[2][4];
    #pragma unroll
    for (int mt = 0; mt < 2; ++mt)
      #pragma unroll
      for (int j = 0; j < 4; ++j)
        acu[mt][j] = (floatx4){ubias[j], ubias[j], ubias[j], ubias[j]};
    #pragma unroll
    for (int ks = 0; ks < 7; ++ks) {
      half8 ah[2], al[2];
      #pragma unroll
      for (int mt = 0; mt < 2; ++mt) {
        int ao = (mt * 16 + l15) * 232 + ks * 32 + quad * 8;
        ah[mt] = *(const half8*)&vAhi[ao];
        al[mt] = *(const half8*)&vAlo[ao];
      }
      #pragma unroll
      for (int j = 0; j < 4; ++j) {
        int nt = 14 + w + 4 * j;
        if (nt < 27) {
          int bo_ = (nt * 16 + l15) * 224 + ks * 32 + quad * 8;
          half8 bh = *(const half8*)&Wch[bo_];
          half8 bl = *(const half8*)&Wcl[bo_];
          #pragma unroll
          for (int mt = 0; mt < 2; ++mt) {
            acu[mt][j] = __builtin_amdgcn_mfma_f32_16x16x32_f16(ah[mt], bh, acu[mt][j], 0, 0, 0);
            acu[mt][j] = __builtin_amdgcn_mfma_f32_16x16x32_f16(ah[mt], bl, acu[mt][j], 0, 0, 0);
            acu[mt][j] = __builtin_amdgcn_mfma_f32_16x16x32_f16(al[mt], bh, acu[mt][j], 0, 0, 0);
          }
        }
      }
    }
    __syncthreads();   // all vA reads (GEMM) done before PV overwrites
    // ---------- PV: h[t][f] = sum_s p[t][s]*u[s][f] ----------
    #pragma unroll
    for (int mt = 0; mt < 2; ++mt) {
      int elem = mt * 4 + quad;
      floatx4 p[4];
      #pragma unroll
      for (int t = 0; t < 4; ++t) p[t] = *(const floatx4*)&Sful[(elem * 4 + t) * 4];
      #pragma unroll
      for (int j = 0; j < 4; ++j) {
        int nt = 14 + w + 4 * j;
        if (nt < 27) {
          int f = (w + 4 * j) * 16 + l15;
          if (f < 196) {
            floatx4 u = acu[mt][j];
            #pragma unroll
            for (int t = 0; t < 4; ++t) {
              float h = p[t][0] * u[0] + p[t][1] * u[1] + p[t][2] * u[2] + p[t][3] * u[3];
              f16 hh = (f16)h;
              int vo = (elem * 4 + t) * 232 + f;
              vAhi[vo] = hh;
              vAlo[vo] = (f16)(h - (float)hh);
            }
          }
        }
      }
    }
    __syncthreads();
  }

  // ---- write h (hi part) to global [32768][800] ----
  for (int idx = tid; idx < 8 * 800; idx += NT) {
    int elem = idx / 800, r = idx - elem * 800;
    f16 v = (f16)0;
    if (r < 784) { int t = r / 196, f = r - t * 196; v = vAhi[(elem * 4 + t) * 232 + f]; }
    hbuf[(size_t)(e0 + elem) * 800 + r] = v;
  }
}

// ---------------- decoder layer GEMM (unchanged) ----------------
__global__ __launch_bounds__(NT, 2)
void k_dec(const f16* __restrict__ A, const f16* __restrict__ Bw,
           const float* __restrict__ bias, f16* __restrict__ C, int do_relu) {
  __shared__ __align__(16) f16 As[128 * 32];
  __shared__ __align__(16) f16 Bs[128 * 32];
  const int tid = threadIdx.x, w = tid >> 6, lane = tid & 63;
  const int l15 = lane & 15, quad = lane >> 4;
  const int m0 = blockIdx.x * 128, n0 = blockIdx.y * 128;
  const int wm = w & 1, wn = w >> 1;
  const int srow = lane >> 2, soff = (lane & 3) * 8;

  floatx4 acc[4][4];
  #pragma unroll
  for (int nt = 0; nt < 4; ++nt) {
    int col = n0 + wn * 64 + nt * 16 + l15;
    float bb = (col < 784) ? bias[col] : 0.f;
    #pragma unroll
    for (int mt = 0; mt < 4; ++mt) acc[mt][nt] = (floatx4){bb, bb, bb, bb};
  }

  for (int kk = 0; kk < 25; ++kk) {
    __syncthreads();
    #pragma unroll
    for (int i = 0; i < 2; ++i) {
      int r = w * 32 + i * 16;
      glds16(&A[(size_t)(m0 + r + srow) * 800 + kk * 32 + soff], &As[r * 32]);
      glds16(&Bw[(size_t)(n0 + r + srow) * 800 + kk * 32 + soff], &Bs[r * 32]);
    }
    __syncthreads();
    half8 af[4], bf[4];
    #pragma unroll
    for (int mt = 0; mt < 4; ++mt)
      af[mt] = *(const half8*)&As[(wm * 64 + mt * 16 + l15) * 32 + quad * 8];
    #pragma unroll
    for (int nt = 0; nt < 4; ++nt)
      bf[nt] = *(const half8*)&Bs[(wn * 64 + nt * 16 + l15) * 32 + quad * 8];
    #pragma unroll
    for (int mt = 0; mt < 4; ++mt)
      #pragma unroll
      for (int nt = 0; nt < 4; ++nt)
        acc[mt][nt] = __builtin_amdgcn_mfma_f32_16x16x32_f16(af[mt], bf[nt], acc[mt][nt], 0, 0, 0);
  }

  #pragma unroll
  for (int nt = 0; nt < 4; ++nt) {
    int gcol = n0 + wn * 64 + nt * 16 + l15;
    if (gcol < 800) {
      #pragma unroll
      for (int mt = 0; mt < 4; ++mt) {
        #pragma unroll
        for (int r = 0; r < 4; ++r) {
          int grow = m0 + wm * 64 + mt * 16 + quad * 4 + r;
          float v = acc[mt][nt][r];
          if (do_relu) v = fmaxf(v, 0.f);
          C[(size_t)grow * 800 + gcol] = (f16)v;
        }
      }
    }
  }
}

// ---------------- logits + softmax (unchanged) ----------------
__global__ __launch_bounds__(NT, 4)
void k_logits(const f16* __restrict__ d2, const float* __restrict__ WoT,
              const float* __restrict__ bo, float* __restrict__ out) {
  __shared__ __align__(16) f16 ds[16 * 800];
  __shared__ float lg[160];
  const int tid = threadIdx.x;
  const size_t e0 = (size_t)blockIdx.x * 16;
  for (int i = tid; i < 16 * 98; i += NT) {
    int e = i / 98, c = (i - e * 98) * 8;
    *(half8*)&ds[e * 800 + c] = *(const half8*)&d2[(e0 + e) * 800 + c];
  }
  __syncthreads();
  {
    int e = tid >> 4, n = tid & 15;
    const f16* dp = &ds[e * 800];
    float s = 0.f;
    #pragma unroll 4
    for (int f = 0; f < 784; ++f) s += (float)dp[f] * WoT[f * 16 + n];
    if (n < 10) lg[e * 10 + n] = s + bo[n];
  }
  __syncthreads();
  if (tid < 16) {
    float l[10], m = -1e30f;
    #pragma unroll
    for (int n = 0; n < 10; ++n) { l[n] = lg[tid * 10 + n]; m = fmaxf(m, l[n]); }
    float sum = 0.f;
    #pragma unroll
    for (int n = 0; n < 10; ++n) { l[n] = __expf(l[n] - m); sum += l[n]; }
    float inv = 1.f / sum;
    #pragma unroll
    for (int n = 0; n < 10; ++n) out[(e0 + tid) * 10 + n] = l[n] * inv;
  }
}

extern "C" void kernel_launch(void* const* d_in, const int* in_sizes, int n_in,
                              void* d_out, int out_size, void* d_ws, size_t ws_size,
                              hipStream_t stream) {
  const float* x   = (const float*)d_in[0];
  const float* W1  = (const float*)d_in[1];
  const float* b1  = (const float*)d_in[2];
  const float* W2  = (const float*)d_in[3];
  // b2 (d_in[4]) cancels in the softmax (row-constant) — unused.
  const float* W3  = (const float*)d_in[5];
  const float* b3  = (const float*)d_in[6];
  const float* Wd1 = (const float*)d_in[7];
  const float* bd1 = (const float*)d_in[8];
  const float* Wd2 = (const float*)d_in[9];
  const float* bd2 = (const float*)d_in[10];
  const float* Wo  = (const float*)d_in[11];
  const float* bo  = (const float*)d_in[12];
  float* out = (float*)d_out;

  char* ws = (char*)d_ws;
  f16*   Wch   = (f16*)ws;
  f16*   Wcl   = (f16*)(ws + WCAP_LO_OFF);
  float* bcap  = (float*)(ws + BCAP_OFF);
  f16*   Wd1p  = (f16*)(ws + WD1_OFF);
  f16*   Wd2p  = (f16*)(ws + WD2_OFF);
  float* WoTws = (float*)(ws + WOT_OFF);
  f16*   hbuf  = (f16*)(ws + HBUF_OFF);
  f16*   d1buf = (f16*)(ws + D1_OFF);

  k_prep_wcap<<<(448 * 224 + NT - 1) / NT, NT, 0, stream>>>(W1, b1, W2, W3, b3, Wch, Wcl, bcap);
  k_prep_wd<<<(896 * 800 + NT - 1) / NT, NT, 0, stream>>>(Wd1, Wd1p);
  k_prep_wd<<<(896 * 800 + NT - 1) / NT, NT, 0, stream>>>(Wd2, Wd2p);
  k_prep_wo<<<(784 * 16 + NT - 1) / NT, NT, 0, stream>>>(Wo, WoTws);

  k_caps<<<32768 / 8, NT, 0, stream>>>(x, Wch, Wcl, bcap, hbuf);
  k_dec<<<dim3(32768 / 128, 7), NT, 0, stream>>>(hbuf, Wd1p, bd1, d1buf, 1);
  k_dec<<<dim3(32768 / 128, 7), NT, 0, stream>>>(d1buf, Wd2p, bd2, hbuf, 0);
  k_logits<<<32768 / 16, NT, 0, stream>>>(hbuf, WoTws, bo, out);
}

// Round 6
// 1214.797 us; speedup vs baseline: 1.1282x; 1.1282x over previous
//
#include <hip/hip_runtime.h>
#include <math.h>

#define NT 256
#define NTC 512
typedef _Float16 f16;
typedef _Float16 half8 __attribute__((ext_vector_type(8)));
typedef float floatx4 __attribute__((ext_vector_type(4)));

// ---------------- workspace layout (bytes) ----------------
#define WCAP_LO_OFF 200704            // Wcap_hi: 448*224*2 @ 0
#define BCAP_OFF    401408            // bcap: 448*4
#define WD1_OFF     403200            // Wd1p: 896*800*2 = 1433600
#define WD2_OFF     1836800           // Wd2p: 1433600
#define WOT_OFF     3270400           // WoT: 784*16*4 = 50176
#define HBUF_OFF    3321856           // h:  32768*800*2 = 52428800
#define D1_OFF      55750656          // d1: 32768*800*2 ; total ~108.2 MB

__device__ inline void glds16(const void* g, void* l) {
  __builtin_amdgcn_global_load_lds((const __attribute__((address_space(1))) void*)g,
                                   (__attribute__((address_space(3))) void*)l, 16, 0, 0);
}

// ---------------- prep kernels ----------------
__global__ void k_prep_wcap(const float* __restrict__ W1, const float* __restrict__ b1,
                            const float* __restrict__ W2,
                            const float* __restrict__ W3, const float* __restrict__ b3,
                            f16* __restrict__ Wch, f16* __restrict__ Wcl,
                            float* __restrict__ bcap) {
  int idx = blockIdx.x * NT + threadIdx.x;
  if (idx >= 448 * 224) return;
  int n = idx / 224, k = idx - n * 224;
  float v = 0.f;
  if (k < 196) {
    if (n < 196) {
      float s = 0.f;
      for (int f = 0; f < 196; ++f) s += W1[f * 196 + k] * W2[f * 196 + n];
      v = s;
    } else if (n == 196) {
      float s = 0.f;
      for (int f = 0; f < 196; ++f) s += b1[f] * W2[f * 196 + k];
      v = s;
    } else if (n >= 224 && n < 420) {
      v = W3[(n - 224) * 196 + k];
    }
  }
  f16 hi = (f16)v;
  Wch[idx] = hi;
  Wcl[idx] = (f16)(v - (float)hi);
  if (k == 0) bcap[n] = (n >= 224 && n < 420) ? b3[n - 224] : 0.f;
}

__global__ void k_prep_wd(const float* __restrict__ Wd, f16* __restrict__ W16) {
  int idx = blockIdx.x * NT + threadIdx.x;
  if (idx >= 896 * 800) return;
  int n = idx / 800, k = idx - n * 800;
  W16[idx] = (f16)((n < 784 && k < 784) ? Wd[n * 784 + k] : 0.f);
}

__global__ void k_prep_wo(const float* __restrict__ Wo, float* __restrict__ WoT) {
  int idx = blockIdx.x * NT + threadIdx.x;
  if (idx >= 784 * 16) return;
  int f = idx >> 4, n = idx & 15;
  WoT[idx] = (n < 10) ? Wo[n * 784 + f] : 0.f;
}

// ---------------- capsule recurrence: 16 elems/wg, 8 waves (NT=512), 2 wg/CU ----------------
// N-split over 8 waves (2 ntiles each), mt=4 (M=64) -> B loaded once per ntile per wg.
__global__ __launch_bounds__(NTC, 4)
void k_caps(const float* __restrict__ x,
            const f16* __restrict__ Wch, const f16* __restrict__ Wcl,
            const float* __restrict__ bcap,
            f16* __restrict__ hbuf) {
  __shared__ __align__(16) char smem[68864];
  f16*   vAhi  = (f16*)smem;                 // [64][232]  (29696 B)
  f16*   vAlo  = (f16*)(smem + 29696);       // [64][232]
  float* Spart = (float*)(smem + 59392);     // [8][64][4] (8192 B)
  float* Sful  = (float*)(smem + 67584);     // [64][4]    (1024 B)
  float* Zl    = (float*)(smem + 68608);     // [64]       (256 B)

  const int tid  = threadIdx.x;
  const int w    = tid >> 6;                 // 0..7
  const int lane = tid & 63;
  const int l15  = lane & 15;
  const int quad = lane >> 4;
  const int e0   = blockIdx.x * 16;

  for (int idx = tid; idx < 16 * 784; idx += NTC) {
    int elem = idx / 784, r = idx - elem * 784;
    int t = r / 196, f = r - t * 196;
    float val = x[(size_t)(e0 + elem) * 784 + r];
    f16 hi = (f16)val;
    int vo = (elem * 4 + t) * 232 + f;
    vAhi[vo] = hi;
    vAlo[vo] = (f16)(val - (float)hi);
  }
  for (int p = tid; p < 64 * 36; p += NTC) {
    int row = p / 36, c = 196 + (p - (p / 36) * 36);
    vAhi[row * 232 + c] = (f16)0;
    vAlo[row * 232 + c] = (f16)0;
  }
  __syncthreads();

  // u bias (constant across iterations): ntile 14+w+8j
  float ubias[2];
  #pragma unroll
  for (int j = 0; j < 2; ++j) {
    int nt = 14 + w + 8 * j;
    ubias[j] = (nt < 27) ? bcap[nt * 16 + l15] : 0.f;
  }

  #pragma unroll 1
  for (int it = 0; it < 8; ++it) {
    // ---------- Phase A: Y GEMM [64 x 208] (ntiles 0..12 split over 8 waves) ----------
    {
      floatx4 acc[4][2];
      #pragma unroll
      for (int mt = 0; mt < 4; ++mt)
        #pragma unroll
        for (int j = 0; j < 2; ++j) acc[mt][j] = (floatx4){0.f, 0.f, 0.f, 0.f};
      #pragma unroll
      for (int ks = 0; ks < 7; ++ks) {
        half8 ah[4], al[4];
        #pragma unroll
        for (int mt = 0; mt < 4; ++mt) {
          int ao = (mt * 16 + l15) * 232 + ks * 32 + quad * 8;
          ah[mt] = *(const half8*)&vAhi[ao];
          al[mt] = *(const half8*)&vAlo[ao];
        }
        #pragma unroll
        for (int j = 0; j < 2; ++j) {
          int nt = w + 8 * j;
          if (nt < 13) {                       // wave-uniform branch
            int bo_ = (nt * 16 + l15) * 224 + ks * 32 + quad * 8;
            half8 bh = *(const half8*)&Wch[bo_];
            half8 bl = *(const half8*)&Wcl[bo_];
            #pragma unroll
            for (int mt = 0; mt < 4; ++mt) {
              acc[mt][j] = __builtin_amdgcn_mfma_f32_16x16x32_f16(ah[mt], bh, acc[mt][j], 0, 0, 0);
              acc[mt][j] = __builtin_amdgcn_mfma_f32_16x16x32_f16(ah[mt], bl, acc[mt][j], 0, 0, 0);
              acc[mt][j] = __builtin_amdgcn_mfma_f32_16x16x32_f16(al[mt], bh, acc[mt][j], 0, 0, 0);
            }
          }
        }
      }
      // Z col 196 = ntile 12 -> w==4, j==1, l15==4
      if (w == 4 && l15 == 4) {
        #pragma unroll
        for (int mt = 0; mt < 4; ++mt) {
          int elem = mt * 4 + quad;
          #pragma unroll
          for (int t = 0; t < 4; ++t) Zl[elem * 4 + t] = acc[mt][1][t];
        }
      }
      // score partials: S[t][s] += Y_t[col] * v_s[col]
      #pragma unroll
      for (int mt = 0; mt < 4; ++mt) {
        int elem = mt * 4 + quad;
        float part[16];
        #pragma unroll
        for (int i = 0; i < 16; ++i) part[i] = 0.f;
        #pragma unroll
        for (int j = 0; j < 2; ++j) {
          int nt = w + 8 * j;
          if (nt < 13) {
            int col = nt * 16 + l15;
            floatx4 c = acc[mt][j];
            #pragma unroll
            for (int s = 0; s < 4; ++s) {
              int vo = (elem * 4 + s) * 232 + col;
              float vv = (float)vAhi[vo] + (float)vAlo[vo];
              #pragma unroll
              for (int t = 0; t < 4; ++t) part[t * 4 + s] += c[t] * vv;
            }
          }
        }
        #pragma unroll
        for (int m = 1; m < 16; m <<= 1) {
          #pragma unroll
          for (int i = 0; i < 16; ++i) part[i] += __shfl_xor(part[i], m, 64);
        }
        if (l15 == 0) {
          #pragma unroll
          for (int i = 0; i < 16; ++i)
            Spart[(w * 64 + elem * 4 + (i >> 2)) * 4 + (i & 3)] = part[i];
        }
      }
    }
    __syncthreads();
    // ---------- softmax ----------
    if (tid < 64) {
      int row = tid, elem = row >> 2;
      float sv[4];
      #pragma unroll
      for (int s = 0; s < 4; ++s) {
        float acc_s = Zl[elem * 4 + s];
        #pragma unroll
        for (int wv = 0; wv < 8; ++wv) acc_s += Spart[(wv * 64 + row) * 4 + s];
        sv[s] = acc_s;
      }
      float m = fmaxf(fmaxf(sv[0], sv[1]), fmaxf(sv[2], sv[3]));
      float ex0 = __expf(sv[0] - m), ex1 = __expf(sv[1] - m);
      float ex2 = __expf(sv[2] - m), ex3 = __expf(sv[3] - m);
      float inv = 1.f / (ex0 + ex1 + ex2 + ex3);
      Sful[row * 4 + 0] = ex0 * inv;
      Sful[row * 4 + 1] = ex1 * inv;
      Sful[row * 4 + 2] = ex2 * inv;
      Sful[row * 4 + 3] = ex3 * inv;
    }
    __syncthreads();
    // ---------- Phase D: u GEMM [64 x 208] (ntiles 14..26 split over 8 waves) ----------
    floatx4 acu[4][2];
    #pragma unroll
    for (int mt = 0; mt < 4; ++mt)
      #pragma unroll
      for (int j = 0; j < 2; ++j)
        acu[mt][j] = (floatx4){ubias[j], ubias[j], ubias[j], ubias[j]};
    #pragma unroll
    for (int ks = 0; ks < 7; ++ks) {
      half8 ah[4], al[4];
      #pragma unroll
      for (int mt = 0; mt < 4; ++mt) {
        int ao = (mt * 16 + l15) * 232 + ks * 32 + quad * 8;
        ah[mt] = *(const half8*)&vAhi[ao];
        al[mt] = *(const half8*)&vAlo[ao];
      }
      #pragma unroll
      for (int j = 0; j < 2; ++j) {
        int nt = 14 + w + 8 * j;
        if (nt < 27) {
          int bo_ = (nt * 16 + l15) * 224 + ks * 32 + quad * 8;
          half8 bh = *(const half8*)&Wch[bo_];
          half8 bl = *(const half8*)&Wcl[bo_];
          #pragma unroll
          for (int mt = 0; mt < 4; ++mt) {
            acu[mt][j] = __builtin_amdgcn_mfma_f32_16x16x32_f16(ah[mt], bh, acu[mt][j], 0, 0, 0);
            acu[mt][j] = __builtin_amdgcn_mfma_f32_16x16x32_f16(ah[mt], bl, acu[mt][j], 0, 0, 0);
            acu[mt][j] = __builtin_amdgcn_mfma_f32_16x16x32_f16(al[mt], bh, acu[mt][j], 0, 0, 0);
          }
        }
      }
    }
    __syncthreads();   // all vA reads (GEMM) done before PV overwrites
    // ---------- PV: h[t][f] = sum_s p[t][s]*u[s][f] ----------
    #pragma unroll
    for (int mt = 0; mt < 4; ++mt) {
      int elem = mt * 4 + quad;
      floatx4 p[4];
      #pragma unroll
      for (int t = 0; t < 4; ++t) p[t] = *(const floatx4*)&Sful[(elem * 4 + t) * 4];
      #pragma unroll
      for (int j = 0; j < 2; ++j) {
        int nt = 14 + w + 8 * j;
        if (nt < 27) {
          int f = (w + 8 * j) * 16 + l15;
          if (f < 196) {
            floatx4 u = acu[mt][j];
            #pragma unroll
            for (int t = 0; t < 4; ++t) {
              float h = p[t][0] * u[0] + p[t][1] * u[1] + p[t][2] * u[2] + p[t][3] * u[3];
              f16 hh = (f16)h;
              int vo = (elem * 4 + t) * 232 + f;
              vAhi[vo] = hh;
              vAlo[vo] = (f16)(h - (float)hh);
            }
          }
        }
      }
    }
    __syncthreads();
  }

  // ---- write h (hi part) to global [32768][800] ----
  for (int idx = tid; idx < 16 * 800; idx += NTC) {
    int elem = idx / 800, r = idx - elem * 800;
    f16 v = (f16)0;
    if (r < 784) { int t = r / 196, f = r - t * 196; v = vAhi[(elem * 4 + t) * 232 + f]; }
    hbuf[(size_t)(e0 + elem) * 800 + r] = v;
  }
}

// ---------------- decoder layer GEMM (unchanged) ----------------
__global__ __launch_bounds__(NT, 2)
void k_dec(const f16* __restrict__ A, const f16* __restrict__ Bw,
           const float* __restrict__ bias, f16* __restrict__ C, int do_relu) {
  __shared__ __align__(16) f16 As[128 * 32];
  __shared__ __align__(16) f16 Bs[128 * 32];
  const int tid = threadIdx.x, w = tid >> 6, lane = tid & 63;
  const int l15 = lane & 15, quad = lane >> 4;
  const int m0 = blockIdx.x * 128, n0 = blockIdx.y * 128;
  const int wm = w & 1, wn = w >> 1;
  const int srow = lane >> 2, soff = (lane & 3) * 8;

  floatx4 acc[4][4];
  #pragma unroll
  for (int nt = 0; nt < 4; ++nt) {
    int col = n0 + wn * 64 + nt * 16 + l15;
    float bb = (col < 784) ? bias[col] : 0.f;
    #pragma unroll
    for (int mt = 0; mt < 4; ++mt) acc[mt][nt] = (floatx4){bb, bb, bb, bb};
  }

  for (int kk = 0; kk < 25; ++kk) {
    __syncthreads();
    #pragma unroll
    for (int i = 0; i < 2; ++i) {
      int r = w * 32 + i * 16;
      glds16(&A[(size_t)(m0 + r + srow) * 800 + kk * 32 + soff], &As[r * 32]);
      glds16(&Bw[(size_t)(n0 + r + srow) * 800 + kk * 32 + soff], &Bs[r * 32]);
    }
    __syncthreads();
    half8 af[4], bf[4];
    #pragma unroll
    for (int mt = 0; mt < 4; ++mt)
      af[mt] = *(const half8*)&As[(wm * 64 + mt * 16 + l15) * 32 + quad * 8];
    #pragma unroll
    for (int nt = 0; nt < 4; ++nt)
      bf[nt] = *(const half8*)&Bs[(wn * 64 + nt * 16 + l15) * 32 + quad * 8];
    #pragma unroll
    for (int mt = 0; mt < 4; ++mt)
      #pragma unroll
      for (int nt = 0; nt < 4; ++nt)
        acc[mt][nt] = __builtin_amdgcn_mfma_f32_16x16x32_f16(af[mt], bf[nt], acc[mt][nt], 0, 0, 0);
  }

  #pragma unroll
  for (int nt = 0; nt < 4; ++nt) {
    int gcol = n0 + wn * 64 + nt * 16 + l15;
    if (gcol < 800) {
      #pragma unroll
      for (int mt = 0; mt < 4; ++mt) {
        #pragma unroll
        for (int r = 0; r < 4; ++r) {
          int grow = m0 + wm * 64 + mt * 16 + quad * 4 + r;
          float v = acc[mt][nt][r];
          if (do_relu) v = fmaxf(v, 0.f);
          C[(size_t)grow * 800 + gcol] = (f16)v;
        }
      }
    }
  }
}

// ---------------- logits + softmax (unchanged) ----------------
__global__ __launch_bounds__(NT, 4)
void k_logits(const f16* __restrict__ d2, const float* __restrict__ WoT,
              const float* __restrict__ bo, float* __restrict__ out) {
  __shared__ __align__(16) f16 ds[16 * 800];
  __shared__ float lg[160];
  const int tid = threadIdx.x;
  const size_t e0 = (size_t)blockIdx.x * 16;
  for (int i = tid; i < 16 * 98; i += NT) {
    int e = i / 98, c = (i - e * 98) * 8;
    *(half8*)&ds[e * 800 + c] = *(const half8*)&d2[(e0 + e) * 800 + c];
  }
  __syncthreads();
  {
    int e = tid >> 4, n = tid & 15;
    const f16* dp = &ds[e * 800];
    float s = 0.f;
    #pragma unroll 4
    for (int f = 0; f < 784; ++f) s += (float)dp[f] * WoT[f * 16 + n];
    if (n < 10) lg[e * 10 + n] = s + bo[n];
  }
  __syncthreads();
  if (tid < 16) {
    float l[10], m = -1e30f;
    #pragma unroll
    for (int n = 0; n < 10; ++n) { l[n] = lg[tid * 10 + n]; m = fmaxf(m, l[n]); }
    float sum = 0.f;
    #pragma unroll
    for (int n = 0; n < 10; ++n) { l[n] = __expf(l[n] - m); sum += l[n]; }
    float inv = 1.f / sum;
    #pragma unroll
    for (int n = 0; n < 10; ++n) out[(e0 + tid) * 10 + n] = l[n] * inv;
  }
}

extern "C" void kernel_launch(void* const* d_in, const int* in_sizes, int n_in,
                              void* d_out, int out_size, void* d_ws, size_t ws_size,
                              hipStream_t stream) {
  const float* x   = (const float*)d_in[0];
  const float* W1  = (const float*)d_in[1];
  const float* b1  = (const float*)d_in[2];
  const float* W2  = (const float*)d_in[3];
  // b2 (d_in[4]) cancels in the softmax (row-constant) — unused.
  const float* W3  = (const float*)d_in[5];
  const float* b3  = (const float*)d_in[6];
  const float* Wd1 = (const float*)d_in[7];
  const float* bd1 = (const float*)d_in[8];
  const float* Wd2 = (const float*)d_in[9];
  const float* bd2 = (const float*)d_in[10];
  const float* Wo  = (const float*)d_in[11];
  const float* bo  = (const float*)d_in[12];
  float* out = (float*)d_out;

  char* ws = (char*)d_ws;
  f16*   Wch   = (f16*)ws;
  f16*   Wcl   = (f16*)(ws + WCAP_LO_OFF);
  float* bcap  = (float*)(ws + BCAP_OFF);
  f16*   Wd1p  = (f16*)(ws + WD1_OFF);
  f16*   Wd2p  = (f16*)(ws + WD2_OFF);
  float* WoTws = (float*)(ws + WOT_OFF);
  f16*   hbuf  = (f16*)(ws + HBUF_OFF);
  f16*   d1buf = (f16*)(ws + D1_OFF);

  k_prep_wcap<<<(448 * 224 + NT - 1) / NT, NT, 0, stream>>>(W1, b1, W2, W3, b3, Wch, Wcl, bcap);
  k_prep_wd<<<(896 * 800 + NT - 1) / NT, NT, 0, stream>>>(Wd1, Wd1p);
  k_prep_wd<<<(896 * 800 + NT - 1) / NT, NT, 0, stream>>>(Wd2, Wd2p);
  k_prep_wo<<<(784 * 16 + NT - 1) / NT, NT, 0, stream>>>(Wo, WoTws);

  k_caps<<<32768 / 16, NTC, 0, stream>>>(x, Wch, Wcl, bcap, hbuf);
  k_dec<<<dim3(32768 / 128, 7), NT, 0, stream>>>(hbuf, Wd1p, bd1, d1buf, 1);
  k_dec<<<dim3(32768 / 128, 7), NT, 0, stream>>>(d1buf, Wd2p, bd2, hbuf, 0);
  k_logits<<<32768 / 16, NT, 0, stream>>>(hbuf, WoTws, bo, out);
}